// Round 7
// baseline (522.226 us; speedup 1.0000x reference)
//
#include <hip/hip_runtime.h>
#include <hip/hip_fp16.h>

#define HID 64

typedef _Float16 half8 __attribute__((ext_vector_type(8)));
typedef _Float16 half4 __attribute__((ext_vector_type(4)));

// ---------------- degree count + per-edge rank (atomic return value) ----------
__global__ void k_count_rank(const int* __restrict__ dst, int* __restrict__ deg,
                             int* __restrict__ rank, int E) {
  int e = blockIdx.x * blockDim.x + threadIdx.x;
  if (e < E) rank[e] = atomicAdd(&deg[dst[e]], 1);
}

// ---------------- exclusive scan of deg -> rowoff (+ fused dis=rsqrt(deg+1)) ----
__global__ void k_scan1(const int* __restrict__ deg, int* __restrict__ scanout,
                        int* __restrict__ blocksums, float* __restrict__ dis, int n) {
  __shared__ int sdata[256];
  int tid = threadIdx.x;
  int base = blockIdx.x * 1024 + tid * 4;
  int v0 = 0, v1 = 0, v2 = 0, v3 = 0;
  if (base + 0 < n) v0 = deg[base + 0];
  if (base + 1 < n) v1 = deg[base + 1];
  if (base + 2 < n) v2 = deg[base + 2];
  if (base + 3 < n) v3 = deg[base + 3];
  if (base + 0 < n) dis[base + 0] = rsqrtf((float)v0 + 1.0f);
  if (base + 1 < n) dis[base + 1] = rsqrtf((float)v1 + 1.0f);
  if (base + 2 < n) dis[base + 2] = rsqrtf((float)v2 + 1.0f);
  if (base + 3 < n) dis[base + 3] = rsqrtf((float)v3 + 1.0f);
  int tsum = v0 + v1 + v2 + v3;
  sdata[tid] = tsum;
  __syncthreads();
  for (int off = 1; off < 256; off <<= 1) {
    int t = (tid >= off) ? sdata[tid - off] : 0;
    __syncthreads();
    sdata[tid] += t;
    __syncthreads();
  }
  int excl = sdata[tid] - tsum;
  if (base + 0 < n) scanout[base + 0] = excl;
  if (base + 1 < n) scanout[base + 1] = excl + v0;
  if (base + 2 < n) scanout[base + 2] = excl + v0 + v1;
  if (base + 3 < n) scanout[base + 3] = excl + v0 + v1 + v2;
  if (tid == 255) blocksums[blockIdx.x] = sdata[255];
}

__global__ void k_scan2(int* blocksums, int nb) {
  __shared__ int s[128];
  int tid = threadIdx.x;
  int v = (tid < nb) ? blocksums[tid] : 0;
  s[tid] = v;
  __syncthreads();
  for (int off = 1; off < 128; off <<= 1) {
    int t = (tid >= off) ? s[tid - off] : 0;
    __syncthreads();
    s[tid] += t;
    __syncthreads();
  }
  if (tid < nb) blocksums[tid] = s[tid] - v;
}

__global__ void k_scan3(const int* __restrict__ scanout,
                        const int* __restrict__ blocksums, int* __restrict__ rowoff,
                        int n) {
  int i = blockIdx.x * blockDim.x + threadIdx.x;
  if (i < n) rowoff[i] = scanout[i] + blocksums[i >> 10];
}

// ---------------- deterministic scatter (no atomics) ----------------
__global__ void k_scatter_det(const int* __restrict__ src, const int* __restrict__ dst,
                              const int* __restrict__ rowoff,
                              const int* __restrict__ rank,
                              int* __restrict__ csr_src, int E) {
  int e = blockIdx.x * blockDim.x + threadIdx.x;
  if (e >= E) return;
  int pos = rowoff[dst[e]] + rank[e];
  csr_src[pos] = src[e];
}

// ---------------- node linear (fp32 in, f16 out) ----------------
__global__ __launch_bounds__(256) void k_lin_f32in(const float* __restrict__ X,
                                                   const float* __restrict__ W,
                                                   __half* __restrict__ Y, int n) {
  int r = blockIdx.x * blockDim.x + threadIdx.x;
  if (r >= n) return;
  float z[HID];
#pragma unroll
  for (int c = 0; c < HID; ++c) z[c] = 0.f;
  const float* xr = X + (long)r * 128;
  for (int kc = 0; kc < 8; ++kc) {
    const float4* xp = (const float4*)(xr + kc * 16);
    float4 a0 = xp[0], a1 = xp[1], a2 = xp[2], a3 = xp[3];
    float ev[16] = {a0.x, a0.y, a0.z, a0.w, a1.x, a1.y, a1.z, a1.w,
                    a2.x, a2.y, a2.z, a2.w, a3.x, a3.y, a3.z, a3.w};
#pragma unroll
    for (int k = 0; k < 16; ++k) {
      const float* wr = W + (kc * 16 + k) * HID;
      float ek = ev[k];
#pragma unroll
      for (int c = 0; c < HID; ++c) z[c] = fmaf(ek, wr[c], z[c]);
    }
  }
  union { __half h[8]; float4 f; } u;
  float4* yr = (float4*)(Y + (long)r * HID);
#pragma unroll
  for (int g = 0; g < 8; ++g) {
#pragma unroll
    for (int j = 0; j < 8; ++j) u.h[j] = __float2half(z[g * 8 + j]);
    yr[g] = u.f;
  }
}

// ---------------- node linear 64->64 (f16 in, f16 out, optional bias) ----------
__global__ __launch_bounds__(256) void k_lin64(const __half* __restrict__ X,
                                               const float* __restrict__ W,
                                               const float* __restrict__ bias,
                                               __half* __restrict__ Y, int n) {
  int r = blockIdx.x * blockDim.x + threadIdx.x;
  if (r >= n) return;
  float z[HID];
  if (bias) {
#pragma unroll
    for (int c = 0; c < HID; ++c) z[c] = bias[c];
  } else {
#pragma unroll
    for (int c = 0; c < HID; ++c) z[c] = 0.f;
  }
  const half8* xr = (const half8*)(X + (long)r * HID);
  for (int kc = 0; kc < 4; ++kc) {
    half8 a0 = xr[kc * 2], a1 = xr[kc * 2 + 1];
    float ev[16];
#pragma unroll
    for (int j = 0; j < 8; ++j) { ev[j] = (float)a0[j]; ev[8 + j] = (float)a1[j]; }
#pragma unroll
    for (int k = 0; k < 16; ++k) {
      const float* wr = W + (kc * 16 + k) * HID;
      float ek = ev[k];
#pragma unroll
      for (int c = 0; c < HID; ++c) z[c] = fmaf(ek, wr[c], z[c]);
    }
  }
  union { __half h[8]; float4 f; } u;
  float4* yr = (float4*)(Y + (long)r * HID);
#pragma unroll
  for (int g = 0; g < 8; ++g) {
#pragma unroll
    for (int j = 0; j < 8; ++j) u.h[j] = __float2half(z[g * 8 + j]);
    yr[g] = u.f;
  }
}

// ---------------- CSR aggregation, quarter-wave per edge ----------------
__global__ __launch_bounds__(256) void k_agg_csr(
    const __half* __restrict__ Hf, const float* __restrict__ dis,
    const int* __restrict__ rowoff, const int* __restrict__ csr_src,
    const float* __restrict__ b, __half* __restrict__ A, int n, int E, int relu) {
  int node = blockIdx.x * 4 + (threadIdx.x >> 6);
  if (node >= n) return;
  int L = threadIdx.x & 63;
  int sub = L >> 4;
  int cq = L & 15;
  const half4* H4 = (const half4*)Hf;
  float dd = dis[node];
  int i0 = rowoff[node];
  int end = (node == n - 1) ? E : rowoff[node + 1];

  float z0[4] = {0.f, 0.f, 0.f, 0.f}, z1[4] = {0.f, 0.f, 0.f, 0.f};
  float z2[4] = {0.f, 0.f, 0.f, 0.f}, z3[4] = {0.f, 0.f, 0.f, 0.f};
  if (sub == 0) {
    half4 hv = H4[(long)node * 16 + cq];
    float w = dd * dd;
#pragma unroll
    for (int j = 0; j < 4; ++j) z0[j] = (float)hv[j] * w;
  }

  int last = end - 1;
  for (int base = i0; base < end; base += 16) {
    float* zp[4] = {z0, z1, z2, z3};
#pragma unroll
    for (int slot = 0; slot < 4; ++slot) {
      int idx = base + slot * 4 + sub;
      int idxc = min(idx, last);
      int s = csr_src[idxc];
      float w = (idx < end) ? dis[s] * dd : 0.f;
      half4 hv = H4[(long)s * 16 + cq];
      float* z = zp[slot];
#pragma unroll
      for (int j = 0; j < 4; ++j) z[j] = fmaf((float)hv[j], w, z[j]);
    }
  }

  float a[4];
#pragma unroll
  for (int j = 0; j < 4; ++j) {
    a[j] = (z0[j] + z1[j]) + (z2[j] + z3[j]);
    a[j] += __shfl_xor(a[j], 16, 64);
    a[j] += __shfl_xor(a[j], 32, 64);
  }
  if (sub == 0) {
    float4 bb = ((const float4*)b)[cq];
    float v0 = a[0] + bb.x, v1 = a[1] + bb.y, v2 = a[2] + bb.z, v3 = a[3] + bb.w;
    if (relu) {
      v0 = fmaxf(v0, 0.f); v1 = fmaxf(v1, 0.f);
      v2 = fmaxf(v2, 0.f); v3 = fmaxf(v3, 0.f);
    }
    half4 o = {(_Float16)v0, (_Float16)v1, (_Float16)v2, (_Float16)v3};
    ((half4*)A)[(long)node * 16 + cq] = o;
  }
}

// ---------------- edge MLP: out_e = relu(U[src]+V[dst]) @ Wc2 + bc2 ----------
// 16 lanes per edge (half4 = 4 channels/lane); 4 slots -> 16 edges per wave iter.
__global__ __launch_bounds__(256) void k_edge_mlp(
    const __half* __restrict__ U, const __half* __restrict__ V,
    const int* __restrict__ src, const int* __restrict__ dst,
    const float* __restrict__ Wc2, const float* __restrict__ bc2,
    float* __restrict__ out, int E, int nwaves) {
  int wid = blockIdx.x * 4 + (threadIdx.x >> 6);
  int L = threadIdx.x & 63;
  int sub = L >> 4;   // which edge of the 4 per slot
  int cq = L & 15;    // channel quad

  float w0[4], w1[4];
#pragma unroll
  for (int j = 0; j < 4; ++j) {
    int c = cq * 4 + j;
    w0[j] = Wc2[2 * c];
    w1[j] = Wc2[2 * c + 1];
  }
  float ob0 = bc2[0], ob1 = bc2[1];

  const half4* U4 = (const half4*)U;
  const half4* V4 = (const half4*)V;
  int last = E - 1;

  for (long base = (long)wid * 16; base < E; base += (long)nwaves * 16) {
    int se[4], de[4];
#pragma unroll
    for (int slot = 0; slot < 4; ++slot) {
      int e = (int)base + slot * 4 + sub;
      int ec = min(e, last);
      se[slot] = src[ec];
      de[slot] = dst[ec];
    }
    half4 uu[4], vv[4];
#pragma unroll
    for (int slot = 0; slot < 4; ++slot) {
      uu[slot] = U4[(long)se[slot] * 16 + cq];
      vv[slot] = V4[(long)de[slot] * 16 + cq];
    }
#pragma unroll
    for (int slot = 0; slot < 4; ++slot) {
      float o0 = 0.f, o1 = 0.f;
#pragma unroll
      for (int j = 0; j < 4; ++j) {
        float v = fmaxf((float)uu[slot][j] + (float)vv[slot][j], 0.f);
        o0 = fmaf(v, w0[j], o0);
        o1 = fmaf(v, w1[j], o1);
      }
      o0 += __shfl_xor(o0, 1, 64);
      o1 += __shfl_xor(o1, 1, 64);
      o0 += __shfl_xor(o0, 2, 64);
      o1 += __shfl_xor(o1, 2, 64);
      o0 += __shfl_xor(o0, 4, 64);
      o1 += __shfl_xor(o1, 4, 64);
      o0 += __shfl_xor(o0, 8, 64);
      o1 += __shfl_xor(o1, 8, 64);
      int e = (int)base + slot * 4 + sub;
      if (cq == 0 && e < E) {
        float2 o = {o0 + ob0, o1 + ob1};
        *(float2*)(out + 2 * (long)e) = o;
      }
    }
  }
}

// ---------------- launch ----------------
extern "C" void kernel_launch(void* const* d_in, const int* in_sizes, int n_in,
                              void* d_out, int out_size, void* d_ws, size_t ws_size,
                              hipStream_t stream) {
  const float* x   = (const float*)d_in[0];
  const int*   ei  = (const int*)d_in[1];
  const float* W1  = (const float*)d_in[2];
  const float* b1  = (const float*)d_in[3];
  const float* W2  = (const float*)d_in[4];
  const float* b2  = (const float*)d_in[5];
  const float* Wc1 = (const float*)d_in[6];
  const float* bc1 = (const float*)d_in[7];
  const float* Wc2 = (const float*)d_in[8];
  const float* bc2 = (const float*)d_in[9];

  const int N = in_sizes[0] / 128;
  const int E = in_sizes[1] / 2;
  const int* src = ei;
  const int* dst = ei + E;

  // workspace layout
  float* dis    = (float*)d_ws;                    // N f32
  __half* y     = (__half*)(dis + N);              // N*64 f16 (aliased by rank)
  __half* h     = y + (long)N * HID;               // N*64 f16
  __half* Ubuf  = h + (long)N * HID;               // N*64 f16
  __half* Vbuf  = Ubuf + (long)N * HID;            // N*64 f16
  int* degi     = (int*)(Vbuf + (long)N * HID);    // N
  int* scanout  = degi + N;                        // N
  int* rowoff   = scanout + N;                     // N
  int* blocksums= rowoff + N;                      // 128
  int* csr_src  = blocksums + 128;                 // E
  int* rank     = (int*)y;  // E ints <= N*64 f16 bytes; dead once y written

  const int B = 256;
  int gN = (N + B - 1) / B;
  int gE = (E + B - 1) / B;
  int nb = (N + 1023) / 1024;

  // ---- CSR build ----
  hipMemsetAsync(degi, 0, (size_t)N * sizeof(int), stream);
  k_count_rank<<<gE, B, 0, stream>>>(dst, degi, rank, E);
  k_scan1<<<nb, B, 0, stream>>>(degi, scanout, blocksums, dis, N);
  k_scan2<<<1, 128, 0, stream>>>(blocksums, nb);
  k_scan3<<<gN, B, 0, stream>>>(scanout, blocksums, rowoff, N);
  k_scatter_det<<<gE, B, 0, stream>>>(src, dst, rowoff, rank, csr_src, E);

  int gAgg = (N + 3) / 4;

  // ---- layer 1 ----
  k_lin_f32in<<<gN, B, 0, stream>>>(x, W1, y, N);
  k_agg_csr<<<gAgg, B, 0, stream>>>(y, dis, rowoff, csr_src, b1, h, N, E, 1);

  // ---- layer 2 ----
  k_lin64<<<gN, B, 0, stream>>>(h, W2, nullptr, y, N);
  k_agg_csr<<<gAgg, B, 0, stream>>>(y, dis, rowoff, csr_src, b2, h, N, E, 0);

  // ---- classifier: U = h@Wc1[:64] + bc1 ; V = h@Wc1[64:] ----
  k_lin64<<<gN, B, 0, stream>>>(h, Wc1, bc1, Ubuf, N);
  k_lin64<<<gN, B, 0, stream>>>(h, Wc1 + 64 * HID, nullptr, Vbuf, N);

  // ---- edge MLP ----
  int cblocks = 2048;
  int nwaves = cblocks * 4;
  k_edge_mlp<<<cblocks, B, 0, stream>>>(Ubuf, Vbuf, src, dst, Wc2, bc2,
                                        (float*)d_out, E, nwaves);
}